// Round 1
// baseline (368.153 us; speedup 1.0000x reference)
//
#include <hip/hip_runtime.h>
#include <hip/hip_bf16.h>

#define SEQ  4096
#define EMB  768
#define NH   12
#define HD   64
#define HID  3072
#define QKVC 2304

typedef __attribute__((ext_vector_type(8))) short bf16x8;
typedef __attribute__((ext_vector_type(4))) float f32x4;

#define MFMA16(a,b,c) __builtin_amdgcn_mfma_f32_16x16x32_bf16(a,b,c,0,0,0)

__device__ __forceinline__ unsigned short f2bf(float f){
  union { float f; unsigned u; } c; c.f = f;
  unsigned r = c.u + 0x7FFFu + ((c.u >> 16) & 1u);
  return (unsigned short)(r >> 16);
}

__device__ __forceinline__ void gload_lds16(const unsigned short* g, unsigned short* l){
  __builtin_amdgcn_global_load_lds(
      (const __attribute__((address_space(1))) unsigned int*)g,
      (__attribute__((address_space(3))) unsigned int*)l, 16, 0, 0);
}

// ---------------- fp32 -> bf16 conversion ----------------
__global__ void cvt_kernel(const float* __restrict__ s, unsigned short* __restrict__ d, int n){
  int i = (blockIdx.x * 256 + threadIdx.x) << 2;
  if (i >= n) return;
  float4 v = *(const float4*)(s + i);
  ushort4 u;
  u.x = f2bf(v.x); u.y = f2bf(v.y); u.z = f2bf(v.z); u.w = f2bf(v.w);
  *(ushort4*)(d + i) = u;
}

// ---------------- LayerNorm (one row per block) ----------------
__global__ __launch_bounds__(256) void ln_kernel(const float* __restrict__ x,
    const float* __restrict__ w, const float* __restrict__ b,
    unsigned short* __restrict__ out)
{
  const int row = blockIdx.x;
  const float* xr = x + (size_t)row * EMB;
  const int t = threadIdx.x;
  float v0 = xr[t], v1 = xr[t + 256], v2 = xr[t + 512];
  float s  = v0 + v1 + v2;
  float s2 = v0*v0 + v1*v1 + v2*v2;
  #pragma unroll
  for (int off = 32; off; off >>= 1){ s += __shfl_down(s, off); s2 += __shfl_down(s2, off); }
  __shared__ float rs[4], rq[4], st[2];
  int wv = t >> 6;
  if ((t & 63) == 0){ rs[wv] = s; rq[wv] = s2; }
  __syncthreads();
  if (t == 0){
    float S  = rs[0] + rs[1] + rs[2] + rs[3];
    float S2 = rq[0] + rq[1] + rq[2] + rq[3];
    float mu  = S * (1.f / 768.f);
    float var = S2 * (1.f / 768.f) - mu * mu;
    st[0] = mu; st[1] = rsqrtf(var + 1e-5f);
  }
  __syncthreads();
  float mu = st[0], rstd = st[1];
  unsigned short* orow = out + (size_t)row * EMB;
  orow[t]       = f2bf((v0 - mu) * rstd * w[t]       + b[t]);
  orow[t + 256] = f2bf((v1 - mu) * rstd * w[t + 256] + b[t + 256]);
  orow[t + 512] = f2bf((v2 - mu) * rstd * w[t + 512] + b[t + 512]);
}

// ---------------- GEMM: C[M,N] = A[M,K] * B[N,K]^T (+bias, epilogue) ----------------
// EPI: 0 = bias -> bf16 out; 1 = bias+GELU -> bf16 out; 2 = bias+residual -> f32 out
// BN in {128, 64}. BM=128, BK=64, 256 threads (4 waves, 2x2 wave grid).
template<int EPI, int BN>
__global__ __launch_bounds__(256, 2) void gemm_kernel(
    const unsigned short* __restrict__ A, const unsigned short* __restrict__ B,
    const float* __restrict__ bias, const float* __restrict__ res,
    unsigned short* __restrict__ Ob, float* __restrict__ Of,
    int M, int N, int K)
{
  constexpr int NF = BN / 32;          // n-frags per wave
  __shared__ unsigned short sA[128 * 64];
  __shared__ unsigned short sB[BN * 64];
  const int tid  = threadIdx.x;
  const int w    = tid >> 6, lane = tid & 63;
  const int wr   = w >> 1,   wc   = w & 1;
  const int l15  = lane & 15, l4  = lane >> 4;
  const int tm   = blockIdx.y, tn = blockIdx.x;
  const unsigned short* Ab = A + (size_t)tm * 128 * K;
  const unsigned short* Bb = B + (size_t)tn * BN  * K;

  f32x4 acc[4][NF];
  #pragma unroll
  for (int m = 0; m < 4; ++m)
    #pragma unroll
    for (int n = 0; n < NF; ++n){ acc[m][n][0]=0.f; acc[m][n][1]=0.f; acc[m][n][2]=0.f; acc[m][n][3]=0.f; }

  const int nk = K >> 6;
  for (int kt = 0; kt < nk; ++kt){
    const int k0 = kt << 6;
    // stage A (1024 chunks of 16B) and B (BN*8 chunks), source-swizzled so LDS
    // chunk (row,kc) holds global chunk (row, kc^(row&7)); reads apply same XOR.
    #pragma unroll
    for (int i = 0; i < 4; ++i){
      int c = i * 256 + tid;
      int row = c >> 3, kc = c & 7;
      int skc = kc ^ (row & 7);
      gload_lds16(Ab + (size_t)row * K + k0 + skc * 8, sA + (i * 256 + w * 64) * 8);
    }
    #pragma unroll
    for (int i = 0; i < NF; ++i){
      int c = i * 256 + tid;
      int row = c >> 3, kc = c & 7;
      int skc = kc ^ (row & 7);
      gload_lds16(Bb + (size_t)row * K + k0 + skc * 8, sB + (i * 256 + w * 64) * 8);
    }
    __syncthreads();
    #pragma unroll
    for (int ks = 0; ks < 2; ++ks){
      bf16x8 af[4], bg[NF];
      #pragma unroll
      for (int m = 0; m < 4; ++m){
        int row = wr * 64 + m * 16 + l15;
        int kc  = ks * 4 + l4;
        af[m] = *(const bf16x8*)&sA[row * 64 + ((kc ^ (row & 7)) << 3)];
      }
      #pragma unroll
      for (int n = 0; n < NF; ++n){
        int row = wc * (BN / 2) + n * 16 + l15;
        int kc  = ks * 4 + l4;
        bg[n] = *(const bf16x8*)&sB[row * 64 + ((kc ^ (row & 7)) << 3)];
      }
      #pragma unroll
      for (int m = 0; m < 4; ++m)
        #pragma unroll
        for (int n = 0; n < NF; ++n)
          acc[m][n] = MFMA16(af[m], bg[n], acc[m][n]);
    }
    __syncthreads();
  }

  #pragma unroll
  for (int m = 0; m < 4; ++m){
    int row0 = tm * 128 + wr * 64 + m * 16 + l4 * 4;
    #pragma unroll
    for (int n = 0; n < NF; ++n){
      int col = tn * BN + wc * (BN / 2) + n * 16 + l15;
      float bv = bias[col];
      #pragma unroll
      for (int r = 0; r < 4; ++r){
        int row = row0 + r;
        float v = acc[m][n][r] + bv;
        if (EPI == 0){
          Ob[(size_t)row * N + col] = f2bf(v);
        } else if (EPI == 1){
          v = 0.5f * v * (1.f + erff(v * 0.70710678118f));
          Ob[(size_t)row * N + col] = f2bf(v);
        } else {
          v += res[(size_t)row * N + col];
          Of[(size_t)row * N + col] = v;
        }
      }
    }
  }
}

// ---------------- flash attention ----------------
// grid (64 q-tiles, 12 heads), 256 threads = 4 waves x 16 q-rows, KVBLK=64.
__global__ __launch_bounds__(256, 2) void attn_kernel(
    const unsigned short* __restrict__ qkv, unsigned short* __restrict__ o)
{
  __shared__ unsigned short sK[64 * 72];   // [kv][d] padded
  __shared__ unsigned short sVt[64 * 72];  // [d][kv] padded (transposed V)
  __shared__ float sP[4][16 * 68];         // per-wave P round-trip
  const int tid = threadIdx.x, w = tid >> 6, lane = tid & 63;
  const int l15 = lane & 15, l4 = lane >> 4;
  const int head = blockIdx.y, qt = blockIdx.x;

  bf16x8 aq[2];
  {
    int qrow = qt * 64 + w * 16 + l15;
    const unsigned short* qp = qkv + (size_t)qrow * QKVC + head * HD + l4 * 8;
    aq[0] = *(const bf16x8*)qp;
    aq[1] = *(const bf16x8*)(qp + 32);
  }
  f32x4 oacc[4];
  float mrun[4], lrun[4];
  #pragma unroll
  for (int i = 0; i < 4; ++i){
    oacc[i][0]=0.f; oacc[i][1]=0.f; oacc[i][2]=0.f; oacc[i][3]=0.f;
    mrun[i] = -3.0e38f; lrun[i] = 0.f;
  }
  const int koff = EMB + head * HD;
  const int voff = 2 * EMB + head * HD;
  float* sPw = sP[w];

  for (int t64 = 0; t64 < 64; ++t64){
    const int kv0 = t64 * 64;
    #pragma unroll
    for (int i = 0; i < 2; ++i){
      int c = i * 256 + tid;
      int kv = c >> 3, kc = c & 7;
      bf16x8 v = *(const bf16x8*)(qkv + (size_t)(kv0 + kv) * QKVC + koff + kc * 8);
      *(bf16x8*)&sK[kv * 72 + kc * 8] = v;
    }
    {
      int kvl = (tid >> 3) * 2, d0 = (tid & 7) * 8;
      const unsigned short* vp = qkv + (size_t)(kv0 + kvl) * QKVC + voff + d0;
      bf16x8 va = *(const bf16x8*)vp;
      bf16x8 vb = *(const bf16x8*)(vp + QKVC);
      #pragma unroll
      for (int i = 0; i < 8; ++i){
        unsigned pk = (unsigned)(unsigned short)va[i] | ((unsigned)(unsigned short)vb[i] << 16);
        *(unsigned*)&sVt[(d0 + i) * 72 + kvl] = pk;
      }
    }
    __syncthreads();

    f32x4 sf[4];
    #pragma unroll
    for (int i = 0; i < 4; ++i){ sf[i][0]=0.f; sf[i][1]=0.f; sf[i][2]=0.f; sf[i][3]=0.f; }
    #pragma unroll
    for (int ks = 0; ks < 2; ++ks){
      #pragma unroll
      for (int nb = 0; nb < 4; ++nb){
        bf16x8 bk = *(const bf16x8*)&sK[(l15 + 16 * nb) * 72 + ks * 32 + l4 * 8];
        sf[nb] = MFMA16(aq[ks], bk, sf[nb]);
      }
    }
    // online softmax, scale = 1/8
    #pragma unroll
    for (int r = 0; r < 4; ++r){
      float mx = fmaxf(fmaxf(sf[0][r], sf[1][r]), fmaxf(sf[2][r], sf[3][r]));
      #pragma unroll
      for (int off = 1; off < 16; off <<= 1) mx = fmaxf(mx, __shfl_xor(mx, off));
      mx *= 0.125f;
      float mn = fmaxf(mrun[r], mx);
      float corr = __builtin_amdgcn_exp2f((mrun[r] - mn) * 1.44269504f);
      mrun[r] = mn;
      float sum = 0.f;
      int qloc = l4 * 4 + r;
      #pragma unroll
      for (int nb = 0; nb < 4; ++nb){
        float p = __builtin_amdgcn_exp2f((sf[nb][r] * 0.125f - mn) * 1.44269504f);
        sPw[qloc * 68 + l15 + 16 * nb] = p;
        sum += p;
      }
      #pragma unroll
      for (int off = 1; off < 16; off <<= 1) sum += __shfl_xor(sum, off);
      lrun[r] = lrun[r] * corr + sum;
      #pragma unroll
      for (int db = 0; db < 4; ++db) oacc[db][r] *= corr;
    }
    // O += P * V
    #pragma unroll
    for (int ks = 0; ks < 2; ++ks){
      const float* pr = &sPw[l15 * 68 + ks * 32 + l4 * 8];
      float4 p0 = *(const float4*)pr;
      float4 p1 = *(const float4*)(pr + 4);
      bf16x8 pa;
      pa[0]=(short)f2bf(p0.x); pa[1]=(short)f2bf(p0.y); pa[2]=(short)f2bf(p0.z); pa[3]=(short)f2bf(p0.w);
      pa[4]=(short)f2bf(p1.x); pa[5]=(short)f2bf(p1.y); pa[6]=(short)f2bf(p1.z); pa[7]=(short)f2bf(p1.w);
      #pragma unroll
      for (int db = 0; db < 4; ++db){
        bf16x8 vb = *(const bf16x8*)&sVt[(l15 + 16 * db) * 72 + ks * 32 + l4 * 8];
        oacc[db] = MFMA16(pa, vb, oacc[db]);
      }
    }
    __syncthreads();
  }

  #pragma unroll
  for (int db = 0; db < 4; ++db){
    #pragma unroll
    for (int r = 0; r < 4; ++r){
      int q = qt * 64 + w * 16 + l4 * 4 + r;
      int d = head * HD + 16 * db + l15;
      o[(size_t)q * EMB + d] = f2bf(oacc[db][r] / lrun[r]);
    }
  }
}

// ---------------- host launch ----------------
extern "C" void kernel_launch(void* const* d_in, const int* in_sizes, int n_in,
                              void* d_out, int out_size, void* d_ws, size_t ws_size,
                              hipStream_t stream)
{
  const float* x    = (const float*)d_in[0];
  const float* ln1w = (const float*)d_in[1];
  const float* ln1b = (const float*)d_in[2];
  const float* qkvw = (const float*)d_in[3];
  const float* qkvb = (const float*)d_in[4];
  const float* outw = (const float*)d_in[5];
  const float* outb = (const float*)d_in[6];
  const float* ln2w = (const float*)d_in[7];
  const float* ln2b = (const float*)d_in[8];
  const float* fc1w = (const float*)d_in[9];
  const float* fc1b = (const float*)d_in[10];
  const float* fc2w = (const float*)d_in[11];
  const float* fc2b = (const float*)d_in[12];
  float* out = (float*)d_out;

  char* ws = (char*)d_ws;
  unsigned short* wqkv = (unsigned short*)ws; ws += (size_t)QKVC * EMB * 2;
  unsigned short* wout = (unsigned short*)ws; ws += (size_t)EMB * EMB * 2;
  unsigned short* wfc1 = (unsigned short*)ws; ws += (size_t)HID * EMB * 2;
  unsigned short* wfc2 = (unsigned short*)ws; ws += (size_t)EMB * HID * 2;
  unsigned short* h1   = (unsigned short*)ws; ws += (size_t)SEQ * EMB * 2;   // reused as attn out
  unsigned short* qkv  = (unsigned short*)ws; ws += (size_t)SEQ * QKVC * 2;  // reused as h2
  unsigned short* h3   = (unsigned short*)ws; ws += (size_t)SEQ * HID * 2;
  unsigned short* attnb = h1;
  unsigned short* h2    = qkv;

  cvt_kernel<<<(QKVC * EMB / 4 + 255) / 256, 256, 0, stream>>>(qkvw, wqkv, QKVC * EMB);
  cvt_kernel<<<(EMB  * EMB / 4 + 255) / 256, 256, 0, stream>>>(outw, wout, EMB * EMB);
  cvt_kernel<<<(HID  * EMB / 4 + 255) / 256, 256, 0, stream>>>(fc1w, wfc1, HID * EMB);
  cvt_kernel<<<(EMB  * HID / 4 + 255) / 256, 256, 0, stream>>>(fc2w, wfc2, EMB * HID);

  ln_kernel<<<SEQ, 256, 0, stream>>>(x, ln1w, ln1b, h1);

  gemm_kernel<0, 128><<<dim3(QKVC / 128, SEQ / 128), 256, 0, stream>>>(
      h1, wqkv, qkvb, nullptr, qkv, nullptr, SEQ, QKVC, EMB);

  attn_kernel<<<dim3(SEQ / 64, NH), 256, 0, stream>>>(qkv, attnb);

  gemm_kernel<2, 64><<<dim3(EMB / 64, SEQ / 128), 256, 0, stream>>>(
      attnb, wout, outb, x, nullptr, out, SEQ, EMB, EMB);

  ln_kernel<<<SEQ, 256, 0, stream>>>(out, ln2w, ln2b, h2);

  gemm_kernel<1, 128><<<dim3(HID / 128, SEQ / 128), 256, 0, stream>>>(
      h2, wfc1, fc1b, nullptr, h3, nullptr, SEQ, HID, EMB);

  gemm_kernel<2, 64><<<dim3(EMB / 64, SEQ / 128), 256, 0, stream>>>(
      h3, wfc2, fc2b, out, nullptr, out, SEQ, EMB, HID);
}

// Round 2
// 346.921 us; speedup vs baseline: 1.0612x; 1.0612x over previous
//
#include <hip/hip_runtime.h>
#include <hip/hip_bf16.h>

#define SEQ  4096
#define EMB  768
#define NH   12
#define HD   64
#define HID  3072
#define QKVC 2304

typedef __attribute__((ext_vector_type(8))) short bf16x8;
typedef __attribute__((ext_vector_type(4))) float f32x4;

#define MFMA16(a,b,c) __builtin_amdgcn_mfma_f32_16x16x32_bf16(a,b,c,0,0,0)

__device__ __forceinline__ unsigned short f2bf(float f){
  union { float f; unsigned u; } c; c.f = f;
  unsigned r = c.u + 0x7FFFu + ((c.u >> 16) & 1u);
  return (unsigned short)(r >> 16);
}

__device__ __forceinline__ void gload_lds16(const unsigned short* g, unsigned short* l){
  __builtin_amdgcn_global_load_lds(
      (const __attribute__((address_space(1))) unsigned int*)g,
      (__attribute__((address_space(3))) unsigned int*)l, 16, 0, 0);
}

// ---------------- fp32 -> bf16 conversion ----------------
__global__ void cvt_kernel(const float* __restrict__ s, unsigned short* __restrict__ d, int n){
  int i = (blockIdx.x * 256 + threadIdx.x) << 2;
  if (i >= n) return;
  float4 v = *(const float4*)(s + i);
  ushort4 u;
  u.x = f2bf(v.x); u.y = f2bf(v.y); u.z = f2bf(v.z); u.w = f2bf(v.w);
  *(ushort4*)(d + i) = u;
}

// ---------------- LayerNorm (one row per block) ----------------
__global__ __launch_bounds__(256) void ln_kernel(const float* __restrict__ x,
    const float* __restrict__ w, const float* __restrict__ b,
    unsigned short* __restrict__ out)
{
  const int row = blockIdx.x;
  const float* xr = x + (size_t)row * EMB;
  const int t = threadIdx.x;
  float v0 = xr[t], v1 = xr[t + 256], v2 = xr[t + 512];
  float s  = v0 + v1 + v2;
  float s2 = v0*v0 + v1*v1 + v2*v2;
  #pragma unroll
  for (int off = 32; off; off >>= 1){ s += __shfl_down(s, off); s2 += __shfl_down(s2, off); }
  __shared__ float rs[4], rq[4], st[2];
  int wv = t >> 6;
  if ((t & 63) == 0){ rs[wv] = s; rq[wv] = s2; }
  __syncthreads();
  if (t == 0){
    float S  = rs[0] + rs[1] + rs[2] + rs[3];
    float S2 = rq[0] + rq[1] + rq[2] + rq[3];
    float mu  = S * (1.f / 768.f);
    float var = S2 * (1.f / 768.f) - mu * mu;
    st[0] = mu; st[1] = rsqrtf(var + 1e-5f);
  }
  __syncthreads();
  float mu = st[0], rstd = st[1];
  unsigned short* orow = out + (size_t)row * EMB;
  orow[t]       = f2bf((v0 - mu) * rstd * w[t]       + b[t]);
  orow[t + 256] = f2bf((v1 - mu) * rstd * w[t + 256] + b[t + 256]);
  orow[t + 512] = f2bf((v2 - mu) * rstd * w[t + 512] + b[t + 512]);
}

// ---------------- GEMM: C[M,N] = A[M,K] * B[N,K]^T (+bias, epilogue) ----------------
// EPI: 0 = bias -> bf16 out; 1 = bias+GELU -> bf16 out; 2 = bias+residual -> f32 out
template<int EPI, int BN>
__global__ __launch_bounds__(256, 2) void gemm_kernel(
    const unsigned short* __restrict__ A, const unsigned short* __restrict__ B,
    const float* __restrict__ bias, const float* __restrict__ res,
    unsigned short* __restrict__ Ob, float* __restrict__ Of,
    int M, int N, int K)
{
  constexpr int NF = BN / 32;          // n-frags per wave
  __shared__ unsigned short sA[128 * 64];
  __shared__ unsigned short sB[BN * 64];
  const int tid  = threadIdx.x;
  const int w    = tid >> 6, lane = tid & 63;
  const int wr   = w >> 1,   wc   = w & 1;
  const int l15  = lane & 15, l4  = lane >> 4;
  const int tm   = blockIdx.y, tn = blockIdx.x;
  const unsigned short* Ab = A + (size_t)tm * 128 * K;
  const unsigned short* Bb = B + (size_t)tn * BN  * K;

  f32x4 acc[4][NF];
  #pragma unroll
  for (int m = 0; m < 4; ++m)
    #pragma unroll
    for (int n = 0; n < NF; ++n){ acc[m][n][0]=0.f; acc[m][n][1]=0.f; acc[m][n][2]=0.f; acc[m][n][3]=0.f; }

  const int nk = K >> 6;
  for (int kt = 0; kt < nk; ++kt){
    const int k0 = kt << 6;
    #pragma unroll
    for (int i = 0; i < 4; ++i){
      int c = i * 256 + tid;
      int row = c >> 3, kc = c & 7;
      int skc = kc ^ (row & 7);
      gload_lds16(Ab + (size_t)row * K + k0 + skc * 8, sA + (i * 256 + w * 64) * 8);
    }
    #pragma unroll
    for (int i = 0; i < NF; ++i){
      int c = i * 256 + tid;
      int row = c >> 3, kc = c & 7;
      int skc = kc ^ (row & 7);
      gload_lds16(Bb + (size_t)row * K + k0 + skc * 8, sB + (i * 256 + w * 64) * 8);
    }
    __syncthreads();
    #pragma unroll
    for (int ks = 0; ks < 2; ++ks){
      bf16x8 af[4], bg[NF];
      #pragma unroll
      for (int m = 0; m < 4; ++m){
        int row = wr * 64 + m * 16 + l15;
        int kc  = ks * 4 + l4;
        af[m] = *(const bf16x8*)&sA[row * 64 + ((kc ^ (row & 7)) << 3)];
      }
      #pragma unroll
      for (int n = 0; n < NF; ++n){
        int row = wc * (BN / 2) + n * 16 + l15;
        int kc  = ks * 4 + l4;
        bg[n] = *(const bf16x8*)&sB[row * 64 + ((kc ^ (row & 7)) << 3)];
      }
      #pragma unroll
      for (int m = 0; m < 4; ++m)
        #pragma unroll
        for (int n = 0; n < NF; ++n)
          acc[m][n] = MFMA16(af[m], bg[n], acc[m][n]);
    }
    __syncthreads();
  }

  #pragma unroll
  for (int m = 0; m < 4; ++m){
    int row0 = tm * 128 + wr * 64 + m * 16 + l4 * 4;
    #pragma unroll
    for (int n = 0; n < NF; ++n){
      int col = tn * BN + wc * (BN / 2) + n * 16 + l15;
      float bv = bias[col];
      #pragma unroll
      for (int r = 0; r < 4; ++r){
        int row = row0 + r;
        float v = acc[m][n][r] + bv;
        if (EPI == 0){
          Ob[(size_t)row * N + col] = f2bf(v);
        } else if (EPI == 1){
          v = 0.5f * v * (1.f + erff(v * 0.70710678118f));
          Ob[(size_t)row * N + col] = f2bf(v);
        } else {
          v += res[(size_t)row * N + col];
          Of[(size_t)row * N + col] = v;
        }
      }
    }
  }
}

// ---------------- flash attention ----------------
// grid (64 q-tiles, 12 heads), 256 threads = 4 waves x 16 q-rows, KVBLK=64.
// Double-buffered K/V, one barrier per tile, async-STAGE split (T14),
// XOR-swizzled sK (gload_lds) and sVt (transpose write), bf16 P round-trip.
__global__ __launch_bounds__(256, 3) void attn_kernel(
    const unsigned short* __restrict__ qkv, unsigned short* __restrict__ o)
{
  __shared__ unsigned short sK[2][64 * 64];   // linear [kv][d], src-swizzled chunks
  __shared__ unsigned short sVt[2][64 * 64];  // [d][kv], pair-XOR swizzled
  __shared__ unsigned short sPb[4][16 * 72];  // per-wave bf16 P (stride 72)
  const int tid = threadIdx.x, w = tid >> 6, lane = tid & 63;
  const int l15 = lane & 15, l4 = lane >> 4;
  const int head = blockIdx.y, qt = blockIdx.x;
  const int koff = EMB + head * HD;
  const int voff = 2 * EMB + head * HD;

  bf16x8 aq[2];
  {
    int qrow = qt * 64 + w * 16 + l15;
    const unsigned short* qp = qkv + (size_t)qrow * QKVC + head * HD + l4 * 8;
    aq[0] = *(const bf16x8*)qp;
    aq[1] = *(const bf16x8*)(qp + 32);
  }
  f32x4 oacc[4];
  float mrun[4], lrun[4];
  #pragma unroll
  for (int i = 0; i < 4; ++i){
    oacc[i][0]=0.f; oacc[i][1]=0.f; oacc[i][2]=0.f; oacc[i][3]=0.f;
    mrun[i] = -3.0e38f; lrun[i] = 0.f;
  }
  unsigned short* sPw = sPb[w];
  const float SCL = 0.125f * 1.44269504f;

  // staging indices (constant per thread)
  const int krow0 = tid >> 3, kck = tid & 7;          // K: chunk (row, kc)
  const int kskc  = kck ^ (krow0 & 7);
  const int kvl   = (tid >> 3) * 2, d0 = (tid & 7) * 8;  // V: 2 kv cols x 8 d rows
  const int vpp   = (tid >> 3) ^ ((tid & 7) << 2);       // swizzled pair slot

  // ---- prologue: stage tile 0 into buf 0 ----
  {
    gload_lds16(qkv + (size_t)krow0 * QKVC + koff + kskc * 8,        &sK[0][(0 * 256 + w * 64) * 8]);
    gload_lds16(qkv + (size_t)(32 + krow0) * QKVC + koff + kskc * 8, &sK[0][(1 * 256 + w * 64) * 8]);
    const unsigned short* vp = qkv + (size_t)kvl * QKVC + voff + d0;
    bf16x8 va = *(const bf16x8*)vp;
    bf16x8 vb = *(const bf16x8*)(vp + QKVC);
    #pragma unroll
    for (int i = 0; i < 8; ++i){
      unsigned pk = (unsigned)(unsigned short)va[i] | ((unsigned)(unsigned short)vb[i] << 16);
      *(unsigned*)&sVt[0][(d0 + i) * 64 + vpp * 2] = pk;
    }
  }

  for (int t64 = 0; t64 < 64; ++t64){
    const int cur = t64 & 1;
    __syncthreads();   // buf[cur] staged; buf[cur^1] free

    bf16x8 va, vb;
    const bool pre = (t64 < 63);
    if (pre){
      const int kv0n = (t64 + 1) * 64;
      gload_lds16(qkv + (size_t)(kv0n + krow0) * QKVC + koff + kskc * 8,      &sK[cur ^ 1][(0 * 256 + w * 64) * 8]);
      gload_lds16(qkv + (size_t)(kv0n + 32 + krow0) * QKVC + koff + kskc * 8, &sK[cur ^ 1][(1 * 256 + w * 64) * 8]);
      const unsigned short* vp = qkv + (size_t)(kv0n + kvl) * QKVC + voff + d0;
      va = *(const bf16x8*)vp;
      vb = *(const bf16x8*)(vp + QKVC);
    }

    // ---- QK^T ----
    f32x4 sf[4];
    #pragma unroll
    for (int i = 0; i < 4; ++i){ sf[i][0]=0.f; sf[i][1]=0.f; sf[i][2]=0.f; sf[i][3]=0.f; }
    #pragma unroll
    for (int ks = 0; ks < 2; ++ks){
      #pragma unroll
      for (int nb = 0; nb < 4; ++nb){
        int row = l15 + 16 * nb;
        int cc  = ks * 4 + l4;
        bf16x8 bk = *(const bf16x8*)&sK[cur][(row * 8 + (cc ^ (row & 7))) * 8];
        sf[nb] = MFMA16(aq[ks], bk, sf[nb]);
      }
    }
    // ---- online softmax (scaled-log2 domain) ----
    #pragma unroll
    for (int r = 0; r < 4; ++r){
      float mx = fmaxf(fmaxf(sf[0][r], sf[1][r]), fmaxf(sf[2][r], sf[3][r]));
      #pragma unroll
      for (int off = 1; off < 16; off <<= 1) mx = fmaxf(mx, __shfl_xor(mx, off));
      mx *= SCL;
      float mn = fmaxf(mrun[r], mx);
      float corr = __builtin_amdgcn_exp2f(mrun[r] - mn);
      mrun[r] = mn;
      float sum = 0.f;
      int qloc = l4 * 4 + r;
      #pragma unroll
      for (int nb = 0; nb < 4; ++nb){
        float p = __builtin_amdgcn_exp2f(sf[nb][r] * SCL - mn);
        sPw[qloc * 72 + l15 + 16 * nb] = f2bf(p);
        sum += p;
      }
      #pragma unroll
      for (int off = 1; off < 16; off <<= 1) sum += __shfl_xor(sum, off);
      lrun[r] = lrun[r] * corr + sum;
      #pragma unroll
      for (int db = 0; db < 4; ++db) oacc[db][r] *= corr;
    }
    // ---- O += P * V ----
    #pragma unroll
    for (int ks = 0; ks < 2; ++ks){
      bf16x8 pa = *(const bf16x8*)&sPw[l15 * 72 + ks * 32 + l4 * 8];
      #pragma unroll
      for (int db = 0; db < 4; ++db){
        int d = l15 + 16 * db;
        int pb = (ks * 16 + l4 * 4) ^ ((((l15 >> 3) + 2 * db) & 7) << 2);
        bf16x8 vv = *(const bf16x8*)&sVt[cur][d * 64 + pb * 2];
        oacc[db] = MFMA16(pa, vv, oacc[db]);
      }
    }
    // ---- commit V for next tile (loads have had QK+softmax+PV to land) ----
    if (pre){
      #pragma unroll
      for (int i = 0; i < 8; ++i){
        unsigned pk = (unsigned)(unsigned short)va[i] | ((unsigned)(unsigned short)vb[i] << 16);
        *(unsigned*)&sVt[cur ^ 1][(d0 + i) * 64 + vpp * 2] = pk;
      }
    }
  }

  #pragma unroll
  for (int db = 0; db < 4; ++db){
    #pragma unroll
    for (int r = 0; r < 4; ++r){
      int q = qt * 64 + w * 16 + l4 * 4 + r;
      int d = head * HD + 16 * db + l15;
      o[(size_t)q * EMB + d] = f2bf(oacc[db][r] / lrun[r]);
    }
  }
}

// ---------------- host launch ----------------
extern "C" void kernel_launch(void* const* d_in, const int* in_sizes, int n_in,
                              void* d_out, int out_size, void* d_ws, size_t ws_size,
                              hipStream_t stream)
{
  const float* x    = (const float*)d_in[0];
  const float* ln1w = (const float*)d_in[1];
  const float* ln1b = (const float*)d_in[2];
  const float* qkvw = (const float*)d_in[3];
  const float* qkvb = (const float*)d_in[4];
  const float* outw = (const float*)d_in[5];
  const float* outb = (const float*)d_in[6];
  const float* ln2w = (const float*)d_in[7];
  const float* ln2b = (const float*)d_in[8];
  const float* fc1w = (const float*)d_in[9];
  const float* fc1b = (const float*)d_in[10];
  const float* fc2w = (const float*)d_in[11];
  const float* fc2b = (const float*)d_in[12];
  float* out = (float*)d_out;

  char* ws = (char*)d_ws;
  unsigned short* wqkv = (unsigned short*)ws; ws += (size_t)QKVC * EMB * 2;
  unsigned short* wout = (unsigned short*)ws; ws += (size_t)EMB * EMB * 2;
  unsigned short* wfc1 = (unsigned short*)ws; ws += (size_t)HID * EMB * 2;
  unsigned short* wfc2 = (unsigned short*)ws; ws += (size_t)EMB * HID * 2;
  unsigned short* h1   = (unsigned short*)ws; ws += (size_t)SEQ * EMB * 2;   // reused as attn out
  unsigned short* qkv  = (unsigned short*)ws; ws += (size_t)SEQ * QKVC * 2;  // reused as h2
  unsigned short* h3   = (unsigned short*)ws; ws += (size_t)SEQ * HID * 2;
  unsigned short* attnb = h1;
  unsigned short* h2    = qkv;

  cvt_kernel<<<(QKVC * EMB / 4 + 255) / 256, 256, 0, stream>>>(qkvw, wqkv, QKVC * EMB);
  cvt_kernel<<<(EMB  * EMB / 4 + 255) / 256, 256, 0, stream>>>(outw, wout, EMB * EMB);
  cvt_kernel<<<(HID  * EMB / 4 + 255) / 256, 256, 0, stream>>>(fc1w, wfc1, HID * EMB);
  cvt_kernel<<<(EMB  * HID / 4 + 255) / 256, 256, 0, stream>>>(fc2w, wfc2, EMB * HID);

  ln_kernel<<<SEQ, 256, 0, stream>>>(x, ln1w, ln1b, h1);

  gemm_kernel<0, 128><<<dim3(QKVC / 128, SEQ / 128), 256, 0, stream>>>(
      h1, wqkv, qkvb, nullptr, qkv, nullptr, SEQ, QKVC, EMB);

  attn_kernel<<<dim3(SEQ / 64, NH), 256, 0, stream>>>(qkv, attnb);

  gemm_kernel<2, 64><<<dim3(EMB / 64, SEQ / 128), 256, 0, stream>>>(
      attnb, wout, outb, x, nullptr, out, SEQ, EMB, EMB);

  ln_kernel<<<SEQ, 256, 0, stream>>>(out, ln2w, ln2b, h2);

  gemm_kernel<1, 128><<<dim3(HID / 128, SEQ / 128), 256, 0, stream>>>(
      h2, wfc1, fc1b, nullptr, h3, nullptr, SEQ, HID, EMB);

  gemm_kernel<2, 64><<<dim3(EMB / 64, SEQ / 128), 256, 0, stream>>>(
      h3, wfc2, fc2b, out, nullptr, out, SEQ, EMB, HID);
}

// Round 3
// 262.606 us; speedup vs baseline: 1.4019x; 1.3211x over previous
//
#include <hip/hip_runtime.h>
#include <hip/hip_bf16.h>

#define SEQ  4096
#define EMB  768
#define NH   12
#define HD   64
#define HID  3072
#define QKVC 2304

typedef __attribute__((ext_vector_type(8))) short bf16x8;
typedef __attribute__((ext_vector_type(4))) float f32x4;

#define MFMA16(a,b,c) __builtin_amdgcn_mfma_f32_16x16x32_bf16(a,b,c,0,0,0)

__device__ __forceinline__ unsigned short f2bf(float f){
  union { float f; unsigned u; } c; c.f = f;
  unsigned r = c.u + 0x7FFFu + ((c.u >> 16) & 1u);
  return (unsigned short)(r >> 16);
}

__device__ __forceinline__ void gload_lds16(const unsigned short* g, unsigned short* l){
  __builtin_amdgcn_global_load_lds(
      (const __attribute__((address_space(1))) unsigned int*)g,
      (__attribute__((address_space(3))) unsigned int*)l, 16, 0, 0);
}

// ---------------- fp32 -> bf16 conversion ----------------
__global__ void cvt_kernel(const float* __restrict__ s, unsigned short* __restrict__ d, int n){
  int i = (blockIdx.x * 256 + threadIdx.x) << 2;
  if (i >= n) return;
  float4 v = *(const float4*)(s + i);
  ushort4 u;
  u.x = f2bf(v.x); u.y = f2bf(v.y); u.z = f2bf(v.z); u.w = f2bf(v.w);
  *(ushort4*)(d + i) = u;
}

// ---------------- LayerNorm (one row per block) ----------------
__global__ __launch_bounds__(256) void ln_kernel(const float* __restrict__ x,
    const float* __restrict__ w, const float* __restrict__ b,
    unsigned short* __restrict__ out)
{
  const int row = blockIdx.x;
  const float* xr = x + (size_t)row * EMB;
  const int t = threadIdx.x;
  float v0 = xr[t], v1 = xr[t + 256], v2 = xr[t + 512];
  float s  = v0 + v1 + v2;
  float s2 = v0*v0 + v1*v1 + v2*v2;
  #pragma unroll
  for (int off = 32; off; off >>= 1){ s += __shfl_down(s, off); s2 += __shfl_down(s2, off); }
  __shared__ float rs[4], rq[4], st[2];
  int wv = t >> 6;
  if ((t & 63) == 0){ rs[wv] = s; rq[wv] = s2; }
  __syncthreads();
  if (t == 0){
    float S  = rs[0] + rs[1] + rs[2] + rs[3];
    float S2 = rq[0] + rq[1] + rq[2] + rq[3];
    float mu  = S * (1.f / 768.f);
    float var = S2 * (1.f / 768.f) - mu * mu;
    st[0] = mu; st[1] = rsqrtf(var + 1e-5f);
  }
  __syncthreads();
  float mu = st[0], rstd = st[1];
  unsigned short* orow = out + (size_t)row * EMB;
  orow[t]       = f2bf((v0 - mu) * rstd * w[t]       + b[t]);
  orow[t + 256] = f2bf((v1 - mu) * rstd * w[t + 256] + b[t + 256]);
  orow[t + 512] = f2bf((v2 - mu) * rstd * w[t + 512] + b[t + 512]);
}

// ---------------- GEMM: C[M,N] = A[M,K] * B[N,K]^T (+bias, epilogue) ----------------
// EPI: 0 = bias -> bf16 out; 1 = bias+GELU -> bf16 out; 2 = bias+residual -> f32 out
template<int EPI, int BN>
__global__ __launch_bounds__(256, 2) void gemm_kernel(
    const unsigned short* __restrict__ A, const unsigned short* __restrict__ B,
    const float* __restrict__ bias, const float* __restrict__ res,
    unsigned short* __restrict__ Ob, float* __restrict__ Of,
    int M, int N, int K)
{
  constexpr int NF = BN / 32;          // n-frags per wave
  __shared__ unsigned short sA[128 * 64];
  __shared__ unsigned short sB[BN * 64];
  const int tid  = threadIdx.x;
  const int w    = tid >> 6, lane = tid & 63;
  const int wr   = w >> 1,   wc   = w & 1;
  const int l15  = lane & 15, l4  = lane >> 4;
  const int tm   = blockIdx.y, tn = blockIdx.x;
  const unsigned short* Ab = A + (size_t)tm * 128 * K;
  const unsigned short* Bb = B + (size_t)tn * BN  * K;

  f32x4 acc[4][NF];
  #pragma unroll
  for (int m = 0; m < 4; ++m)
    #pragma unroll
    for (int n = 0; n < NF; ++n){ acc[m][n][0]=0.f; acc[m][n][1]=0.f; acc[m][n][2]=0.f; acc[m][n][3]=0.f; }

  const int nk = K >> 6;
  for (int kt = 0; kt < nk; ++kt){
    const int k0 = kt << 6;
    #pragma unroll
    for (int i = 0; i < 4; ++i){
      int c = i * 256 + tid;
      int row = c >> 3, kc = c & 7;
      int skc = kc ^ (row & 7);
      gload_lds16(Ab + (size_t)row * K + k0 + skc * 8, sA + (i * 256 + w * 64) * 8);
    }
    #pragma unroll
    for (int i = 0; i < NF; ++i){
      int c = i * 256 + tid;
      int row = c >> 3, kc = c & 7;
      int skc = kc ^ (row & 7);
      gload_lds16(Bb + (size_t)row * K + k0 + skc * 8, sB + (i * 256 + w * 64) * 8);
    }
    __syncthreads();
    #pragma unroll
    for (int ks = 0; ks < 2; ++ks){
      bf16x8 af[4], bg[NF];
      #pragma unroll
      for (int m = 0; m < 4; ++m){
        int row = wr * 64 + m * 16 + l15;
        int kc  = ks * 4 + l4;
        af[m] = *(const bf16x8*)&sA[row * 64 + ((kc ^ (row & 7)) << 3)];
      }
      #pragma unroll
      for (int n = 0; n < NF; ++n){
        int row = wc * (BN / 2) + n * 16 + l15;
        int kc  = ks * 4 + l4;
        bg[n] = *(const bf16x8*)&sB[row * 64 + ((kc ^ (row & 7)) << 3)];
      }
      #pragma unroll
      for (int m = 0; m < 4; ++m)
        #pragma unroll
        for (int n = 0; n < NF; ++n)
          acc[m][n] = MFMA16(af[m], bg[n], acc[m][n]);
    }
    __syncthreads();
  }

  #pragma unroll
  for (int m = 0; m < 4; ++m){
    int row0 = tm * 128 + wr * 64 + m * 16 + l4 * 4;
    #pragma unroll
    for (int n = 0; n < NF; ++n){
      int col = tn * BN + wc * (BN / 2) + n * 16 + l15;
      float bv = bias[col];
      #pragma unroll
      for (int r = 0; r < 4; ++r){
        int row = row0 + r;
        float v = acc[m][n][r] + bv;
        if (EPI == 0){
          Ob[(size_t)row * N + col] = f2bf(v);
        } else if (EPI == 1){
          v = 0.5f * v * (1.f + erff(v * 0.70710678118f));
          Ob[(size_t)row * N + col] = f2bf(v);
        } else {
          v += res[(size_t)row * N + col];
          Of[(size_t)row * N + col] = v;
        }
      }
    }
  }
}

// ---------------- flash attention (swapped-operand form) ----------------
// 768 blocks (XCD-remapped), 4 waves x 16 q-rows, KVBLK=64.
// QK^T swapped: sf = mfma(K,Q) -> lane holds S^T[kv=16nb+4*l4+r][q=l15]:
// softmax is 15 local fmax + 2 shfl_xor. PV swapped: oT = mfma(V^T, P^T).
// sVt chunk swizzle c^((d>>3)&7)^(d&7): conflict-free writes AND reads.
__global__ __launch_bounds__(256, 3) void attn_kernel(
    const unsigned short* __restrict__ qkv, unsigned short* __restrict__ o)
{
  __shared__ unsigned short sK[2][64 * 64];   // [kv][d] linear, src-swizzled chunks
  __shared__ unsigned short sVt[2][64 * 64];  // [d][kv], chunk-XOR swizzled
  __shared__ unsigned short sPb[4][16 * 72];  // per-wave bf16 P^T rows [q][kv]
  const int tid = threadIdx.x, w = tid >> 6, lane = tid & 63;
  const int l15 = lane & 15, l4 = lane >> 4;

  // XCD-aware remap: each XCD's resident blocks cover <=2 heads (KV fits L2)
  const int bid  = blockIdx.x;
  const int v_id = (bid & 7) * 96 + (bid >> 3);
  const int head = v_id >> 6, qt = v_id & 63;

  const int koff = EMB + head * HD;
  const int voff = 2 * EMB + head * HD;
  const int qbase = qt * 64 + w * 16;

  // Q as B-frag: lane holds Q[q=qbase+l15][d=32ks+8*l4+j]
  bf16x8 qf[2];
  {
    const unsigned short* qp = qkv + (size_t)(qbase + l15) * QKVC + head * HD + l4 * 8;
    qf[0] = *(const bf16x8*)qp;
    qf[1] = *(const bf16x8*)(qp + 32);
  }
  f32x4 oaccT[4];
  #pragma unroll
  for (int i = 0; i < 4; ++i){ oaccT[i][0]=0.f; oaccT[i][1]=0.f; oaccT[i][2]=0.f; oaccT[i][3]=0.f; }
  float mrun = -3.0e38f, lrun = 0.f;
  unsigned short* sPw = sPb[w];
  const float SCL = 0.125f * 1.44269504f;

  // staging indices
  const int krow0 = tid >> 3, kskc = (tid & 7) ^ (krow0 & 7);  // K chunks
  const int vp_   = tid >> 3;                 // V kv-pair index (pair p)
  const int d0    = (tid & 7) * 8;            // V d-range
  const int vph   = vp_ >> 2, vpl = vp_ & 3;  // chunk base / slot

  // ---- prologue: stage tile 0 into buf 0 ----
  {
    gload_lds16(qkv + (size_t)krow0 * QKVC + koff + kskc * 8,        &sK[0][(w * 64) * 8]);
    gload_lds16(qkv + (size_t)(32 + krow0) * QKVC + koff + kskc * 8, &sK[0][(256 + w * 64) * 8]);
    const unsigned short* vp = qkv + (size_t)(vp_ * 2) * QKVC + voff + d0;
    bf16x8 va = *(const bf16x8*)vp;
    bf16x8 vb = *(const bf16x8*)(vp + QKVC);
    #pragma unroll
    for (int i = 0; i < 8; ++i){
      unsigned pk = (unsigned)(unsigned short)va[i] | ((unsigned)(unsigned short)vb[i] << 16);
      int cp = vph ^ (tid & 7) ^ i;
      *(unsigned*)&sVt[0][(d0 + i) * 64 + cp * 8 + vpl * 2] = pk;
    }
  }

  for (int t64 = 0; t64 < 64; ++t64){
    const int cur = t64 & 1;
    __syncthreads();   // buf[cur] staged; buf[cur^1] free

    bf16x8 va, vb;
    const bool pre = (t64 < 63);
    if (pre){
      const int kv0n = (t64 + 1) * 64;
      gload_lds16(qkv + (size_t)(kv0n + krow0) * QKVC + koff + kskc * 8,      &sK[cur ^ 1][(w * 64) * 8]);
      gload_lds16(qkv + (size_t)(kv0n + 32 + krow0) * QKVC + koff + kskc * 8, &sK[cur ^ 1][(256 + w * 64) * 8]);
      const unsigned short* vp = qkv + (size_t)(kv0n + vp_ * 2) * QKVC + voff + d0;
      va = *(const bf16x8*)vp;
      vb = *(const bf16x8*)(vp + QKVC);
    }

    // ---- QK^T (swapped): sf[nb] = S^T[kv=16nb+4*l4+r][q=l15] ----
    f32x4 sf[4];
    #pragma unroll
    for (int i = 0; i < 4; ++i){ sf[i][0]=0.f; sf[i][1]=0.f; sf[i][2]=0.f; sf[i][3]=0.f; }
    __builtin_amdgcn_s_setprio(1);
    #pragma unroll
    for (int ks = 0; ks < 2; ++ks){
      #pragma unroll
      for (int nb = 0; nb < 4; ++nb){
        int row = 16 * nb + l15;
        bf16x8 kf = *(const bf16x8*)&sK[cur][(row * 8 + ((4 * ks + l4) ^ (row & 7))) * 8];
        sf[nb] = MFMA16(kf, qf[ks], sf[nb]);
      }
    }
    __builtin_amdgcn_s_setprio(0);

    // ---- online softmax: per-lane row (q=l15), 16 kv values in regs ----
    float mloc = sf[0][0];
    #pragma unroll
    for (int nb = 0; nb < 4; ++nb)
      #pragma unroll
      for (int r = 0; r < 4; ++r) mloc = fmaxf(mloc, sf[nb][r]);
    mloc *= SCL;
    float mx = fmaxf(mloc, __shfl_xor(mloc, 16));
    mx = fmaxf(mx, __shfl_xor(mx, 32));
    if (!__all(mx <= mrun + 8.f)){       // T13 defer-max
      float mn = fmaxf(mrun, mx);
      float corr = __builtin_amdgcn_exp2f(mrun - mn);
      mrun = mn;
      lrun *= corr;
      #pragma unroll
      for (int db = 0; db < 4; ++db)
        #pragma unroll
        for (int r = 0; r < 4; ++r) oaccT[db][r] *= corr;
    }
    float p[4][4];
    float ps = 0.f;
    #pragma unroll
    for (int nb = 0; nb < 4; ++nb)
      #pragma unroll
      for (int r = 0; r < 4; ++r){
        float pv = __builtin_amdgcn_exp2f(sf[nb][r] * SCL - mrun);
        p[nb][r] = pv; ps += pv;
      }
    ps += __shfl_xor(ps, 16);
    ps += __shfl_xor(ps, 32);
    lrun += ps;
    // pack P^T rows: [q=l15][kv=16nb+4*l4+2dw..+1] as b32 pairs
    #pragma unroll
    for (int nb = 0; nb < 4; ++nb)
      #pragma unroll
      for (int dw = 0; dw < 2; ++dw){
        unsigned pk = (unsigned)f2bf(p[nb][2 * dw]) | ((unsigned)f2bf(p[nb][2 * dw + 1]) << 16);
        *(unsigned*)&sPw[l15 * 72 + 16 * nb + 4 * l4 + 2 * dw] = pk;
      }

    // ---- O^T += V^T * P^T ----
    __builtin_amdgcn_s_setprio(1);
    #pragma unroll
    for (int ks = 0; ks < 2; ++ks){
      bf16x8 pb = *(const bf16x8*)&sPw[l15 * 72 + ks * 32 + l4 * 8];
      #pragma unroll
      for (int db = 0; db < 4; ++db){
        int d = 16 * db + l15;
        int cp = (4 * ks + l4) ^ ((d >> 3) & 7) ^ (d & 7);
        bf16x8 vv = *(const bf16x8*)&sVt[cur][d * 64 + cp * 8];
        oaccT[db] = MFMA16(vv, pb, oaccT[db]);
      }
    }
    __builtin_amdgcn_s_setprio(0);

    // ---- commit next tile's V (loads had QK+softmax+PV to land) ----
    if (pre){
      #pragma unroll
      for (int i = 0; i < 8; ++i){
        unsigned pk = (unsigned)(unsigned short)va[i] | ((unsigned)(unsigned short)vb[i] << 16);
        int cp = vph ^ (tid & 7) ^ i;
        *(unsigned*)&sVt[cur ^ 1][(d0 + i) * 64 + cp * 8 + vpl * 2] = pk;
      }
    }
  }

  // ---- epilogue: O^T -> O via per-wave sP buffer ----
  {
    float inv = 1.f / lrun;
    #pragma unroll
    for (int db = 0; db < 4; ++db)
      #pragma unroll
      for (int dw = 0; dw < 2; ++dw){
        unsigned pk = (unsigned)f2bf(oaccT[db][2 * dw] * inv) |
                      ((unsigned)f2bf(oaccT[db][2 * dw + 1] * inv) << 16);
        *(unsigned*)&sPw[l15 * 72 + 16 * db + 4 * l4 + 2 * dw] = pk;
      }
    // wave-local RW ordering handled by compiler lgkmcnt
    int qe = lane >> 2, de = (lane & 3) * 16;
    bf16x8 r0 = *(const bf16x8*)&sPw[qe * 72 + de];
    bf16x8 r1 = *(const bf16x8*)&sPw[qe * 72 + de + 8];
    unsigned short* op = o + (size_t)(qbase + qe) * EMB + head * HD + de;
    *(bf16x8*)op = r0;
    *(bf16x8*)(op + 8) = r1;
  }
}

// ---------------- host launch ----------------
extern "C" void kernel_launch(void* const* d_in, const int* in_sizes, int n_in,
                              void* d_out, int out_size, void* d_ws, size_t ws_size,
                              hipStream_t stream)
{
  const float* x    = (const float*)d_in[0];
  const float* ln1w = (const float*)d_in[1];
  const float* ln1b = (const float*)d_in[2];
  const float* qkvw = (const float*)d_in[3];
  const float* qkvb = (const float*)d_in[4];
  const float* outw = (const float*)d_in[5];
  const float* outb = (const float*)d_in[6];
  const float* ln2w = (const float*)d_in[7];
  const float* ln2b = (const float*)d_in[8];
  const float* fc1w = (const float*)d_in[9];
  const float* fc1b = (const float*)d_in[10];
  const float* fc2w = (const float*)d_in[11];
  const float* fc2b = (const float*)d_in[12];
  float* out = (float*)d_out;

  char* ws = (char*)d_ws;
  unsigned short* wqkv = (unsigned short*)ws; ws += (size_t)QKVC * EMB * 2;
  unsigned short* wout = (unsigned short*)ws; ws += (size_t)EMB * EMB * 2;
  unsigned short* wfc1 = (unsigned short*)ws; ws += (size_t)HID * EMB * 2;
  unsigned short* wfc2 = (unsigned short*)ws; ws += (size_t)EMB * HID * 2;
  unsigned short* h1   = (unsigned short*)ws; ws += (size_t)SEQ * EMB * 2;   // reused as attn out
  unsigned short* qkv  = (unsigned short*)ws; ws += (size_t)SEQ * QKVC * 2;  // reused as h2
  unsigned short* h3   = (unsigned short*)ws; ws += (size_t)SEQ * HID * 2;
  unsigned short* attnb = h1;
  unsigned short* h2    = qkv;

  cvt_kernel<<<(QKVC * EMB / 4 + 255) / 256, 256, 0, stream>>>(qkvw, wqkv, QKVC * EMB);
  cvt_kernel<<<(EMB  * EMB / 4 + 255) / 256, 256, 0, stream>>>(outw, wout, EMB * EMB);
  cvt_kernel<<<(HID  * EMB / 4 + 255) / 256, 256, 0, stream>>>(fc1w, wfc1, HID * EMB);
  cvt_kernel<<<(EMB  * HID / 4 + 255) / 256, 256, 0, stream>>>(fc2w, wfc2, EMB * HID);

  ln_kernel<<<SEQ, 256, 0, stream>>>(x, ln1w, ln1b, h1);

  gemm_kernel<0, 128><<<dim3(QKVC / 128, SEQ / 128), 256, 0, stream>>>(
      h1, wqkv, qkvb, nullptr, qkv, nullptr, SEQ, QKVC, EMB);

  attn_kernel<<<SEQ / 64 * NH, 256, 0, stream>>>(qkv, attnb);

  gemm_kernel<2, 64><<<dim3(EMB / 64, SEQ / 128), 256, 0, stream>>>(
      attnb, wout, outb, x, nullptr, out, SEQ, EMB, EMB);

  ln_kernel<<<SEQ, 256, 0, stream>>>(out, ln2w, ln2b, h2);

  gemm_kernel<1, 128><<<dim3(HID / 128, SEQ / 128), 256, 0, stream>>>(
      h2, wfc1, fc1b, nullptr, h3, nullptr, SEQ, HID, EMB);

  gemm_kernel<2, 64><<<dim3(EMB / 64, SEQ / 128), 256, 0, stream>>>(
      h3, wfc2, fc2b, out, nullptr, out, SEQ, EMB, HID);
}

// Round 5
// 255.958 us; speedup vs baseline: 1.4383x; 1.0260x over previous
//
#include <hip/hip_runtime.h>
#include <hip/hip_bf16.h>

#define SEQ  4096
#define EMB  768
#define NH   12
#define HD   64
#define HID  3072
#define QKVC 2304

typedef __attribute__((ext_vector_type(8))) short bf16x8;
typedef __attribute__((ext_vector_type(4))) float f32x4;

#define MFMA16(a,b,c) __builtin_amdgcn_mfma_f32_16x16x32_bf16(a,b,c,0,0,0)

__device__ __forceinline__ unsigned short f2bf(float f){
  union { float f; unsigned u; } c; c.f = f;
  unsigned r = c.u + 0x7FFFu + ((c.u >> 16) & 1u);
  return (unsigned short)(r >> 16);
}

__device__ __forceinline__ unsigned cvtpk(float a, float b){
  unsigned r;
  asm("v_cvt_pk_bf16_f32 %0, %1, %2" : "=v"(r) : "v"(a), "v"(b));
  return r;
}

__device__ __forceinline__ void gload_lds16(const unsigned short* g, unsigned short* l){
  __builtin_amdgcn_global_load_lds(
      (const __attribute__((address_space(1))) unsigned int*)g,
      (__attribute__((address_space(3))) unsigned int*)l, 16, 0, 0);
}

// ---------------- fp32 -> bf16 conversion ----------------
__global__ void cvt_kernel(const float* __restrict__ s, unsigned short* __restrict__ d, int n){
  int i = (blockIdx.x * 256 + threadIdx.x) << 2;
  if (i >= n) return;
  float4 v = *(const float4*)(s + i);
  ushort4 u;
  u.x = f2bf(v.x); u.y = f2bf(v.y); u.z = f2bf(v.z); u.w = f2bf(v.w);
  *(ushort4*)(d + i) = u;
}

// ---------------- LayerNorm (one row per block) ----------------
__global__ __launch_bounds__(256) void ln_kernel(const float* __restrict__ x,
    const float* __restrict__ w, const float* __restrict__ b,
    unsigned short* __restrict__ out)
{
  const int row = blockIdx.x;
  const float* xr = x + (size_t)row * EMB;
  const int t = threadIdx.x;
  float v0 = xr[t], v1 = xr[t + 256], v2 = xr[t + 512];
  float s  = v0 + v1 + v2;
  float s2 = v0*v0 + v1*v1 + v2*v2;
  #pragma unroll
  for (int off = 32; off; off >>= 1){ s += __shfl_down(s, off); s2 += __shfl_down(s2, off); }
  __shared__ float rs[4], rq[4], st[2];
  int wv = t >> 6;
  if ((t & 63) == 0){ rs[wv] = s; rq[wv] = s2; }
  __syncthreads();
  if (t == 0){
    float S  = rs[0] + rs[1] + rs[2] + rs[3];
    float S2 = rq[0] + rq[1] + rq[2] + rq[3];
    float mu  = S * (1.f / 768.f);
    float var = S2 * (1.f / 768.f) - mu * mu;
    st[0] = mu; st[1] = rsqrtf(var + 1e-5f);
  }
  __syncthreads();
  float mu = st[0], rstd = st[1];
  unsigned short* orow = out + (size_t)row * EMB;
  orow[t]       = f2bf((v0 - mu) * rstd * w[t]       + b[t]);
  orow[t + 256] = f2bf((v1 - mu) * rstd * w[t + 256] + b[t + 256]);
  orow[t + 512] = f2bf((v2 - mu) * rstd * w[t + 512] + b[t + 512]);
}

// ---------------- GEMM: C[M,N] = A[M,K] * B[N,K]^T (+bias, epilogue) ----------------
// EPI: 0 = bias -> bf16 out; 1 = bias+GELU -> bf16 out; 2 = bias+residual -> f32 out
template<int EPI, int BN>
__global__ __launch_bounds__(256, 2) void gemm_kernel(
    const unsigned short* __restrict__ A, const unsigned short* __restrict__ B,
    const float* __restrict__ bias, const float* __restrict__ res,
    unsigned short* __restrict__ Ob, float* __restrict__ Of,
    int M, int N, int K)
{
  constexpr int NF = BN / 32;          // n-frags per wave
  __shared__ unsigned short sA[128 * 64];
  __shared__ unsigned short sB[BN * 64];
  const int tid  = threadIdx.x;
  const int w    = tid >> 6, lane = tid & 63;
  const int wr   = w >> 1,   wc   = w & 1;
  const int l15  = lane & 15, l4  = lane >> 4;
  const int tm   = blockIdx.y, tn = blockIdx.x;
  const unsigned short* Ab = A + (size_t)tm * 128 * K;
  const unsigned short* Bb = B + (size_t)tn * BN  * K;

  f32x4 acc[4][NF];
  #pragma unroll
  for (int m = 0; m < 4; ++m)
    #pragma unroll
    for (int n = 0; n < NF; ++n){ acc[m][n][0]=0.f; acc[m][n][1]=0.f; acc[m][n][2]=0.f; acc[m][n][3]=0.f; }

  const int nk = K >> 6;
  for (int kt = 0; kt < nk; ++kt){
    const int k0 = kt << 6;
    #pragma unroll
    for (int i = 0; i < 4; ++i){
      int c = i * 256 + tid;
      int row = c >> 3, kc = c & 7;
      int skc = kc ^ (row & 7);
      gload_lds16(Ab + (size_t)row * K + k0 + skc * 8, sA + (i * 256 + w * 64) * 8);
    }
    #pragma unroll
    for (int i = 0; i < NF; ++i){
      int c = i * 256 + tid;
      int row = c >> 3, kc = c & 7;
      int skc = kc ^ (row & 7);
      gload_lds16(Bb + (size_t)row * K + k0 + skc * 8, sB + (i * 256 + w * 64) * 8);
    }
    __syncthreads();
    #pragma unroll
    for (int ks = 0; ks < 2; ++ks){
      bf16x8 af[4], bg[NF];
      #pragma unroll
      for (int m = 0; m < 4; ++m){
        int row = wr * 64 + m * 16 + l15;
        int kc  = ks * 4 + l4;
        af[m] = *(const bf16x8*)&sA[row * 64 + ((kc ^ (row & 7)) << 3)];
      }
      #pragma unroll
      for (int n = 0; n < NF; ++n){
        int row = wc * (BN / 2) + n * 16 + l15;
        int kc  = ks * 4 + l4;
        bg[n] = *(const bf16x8*)&sB[row * 64 + ((kc ^ (row & 7)) << 3)];
      }
      #pragma unroll
      for (int m = 0; m < 4; ++m)
        #pragma unroll
        for (int n = 0; n < NF; ++n)
          acc[m][n] = MFMA16(af[m], bg[n], acc[m][n]);
    }
    __syncthreads();
  }

  #pragma unroll
  for (int m = 0; m < 4; ++m){
    int row0 = tm * 128 + wr * 64 + m * 16 + l4 * 4;
    #pragma unroll
    for (int n = 0; n < NF; ++n){
      int col = tn * BN + wc * (BN / 2) + n * 16 + l15;
      float bv = bias[col];
      #pragma unroll
      for (int r = 0; r < 4; ++r){
        int row = row0 + r;
        float v = acc[m][n][r] + bv;
        if (EPI == 0){
          Ob[(size_t)row * N + col] = f2bf(v);
        } else if (EPI == 1){
          v = 0.5f * v * (1.f + erff(v * 0.70710678118f));
          Ob[(size_t)row * N + col] = f2bf(v);
        } else {
          v += res[(size_t)row * N + col];
          Of[(size_t)row * N + col] = v;
        }
      }
    }
  }
}

// ---------------- flash attention v4 ----------------
// 384 blocks (XCD-pinned heads), 4 waves x 32 q-rows (128-q blocks), KVBLK=64.
// Swapped QK^T (softmax lane-local). In-register P: B-slot (l4,j) holds
// kv = 32ks+16(j>>2)+4l4+(j&3). V is placed into sVt PRE-PERMUTED so the
// R3-proven natural-chunk ds_read_b128 delivers exactly that kv order:
// position pair q holds kv-pair w16 with q = b0(w16)|b3(w16)<<1|b21(w16)<<2.
__global__ __launch_bounds__(256, 2) void attn_kernel(
    const unsigned short* __restrict__ qkv, unsigned short* __restrict__ o)
{
  __shared__ unsigned short sK[2][64 * 64];   // [kv][d] linear, src-swizzled chunks
  __shared__ unsigned short sVt[2][64 * 64];  // [d][kv-permuted], chunk-XOR swizzled
  __shared__ unsigned short sEp[4][16 * 72];  // per-wave epilogue scratch
  const int tid = threadIdx.x, w = tid >> 6, lane = tid & 63;
  const int l15 = lane & 15, l4 = lane >> 4;

  const int bid  = blockIdx.x;
  const int v_id = (bid & 7) * 48 + (bid >> 3);
  const int head = v_id >> 5, qt = v_id & 31;

  const int koff = EMB + head * HD;
  const int voff = 2 * EMB + head * HD;
  const int qbase = qt * 128 + w * 32;

  // Q as B-frags: qf[qg][ks], lane holds Q[q=qbase+16qg+l15][d=32ks+8l4+j]
  bf16x8 qf[2][2];
  #pragma unroll
  for (int qg = 0; qg < 2; ++qg){
    const unsigned short* qp = qkv + (size_t)(qbase + qg * 16 + l15) * QKVC + head * HD + l4 * 8;
    qf[qg][0] = *(const bf16x8*)qp;
    qf[qg][1] = *(const bf16x8*)(qp + 32);
  }

  f32x4 oaccT[4][2];
  #pragma unroll
  for (int i = 0; i < 4; ++i)
    #pragma unroll
    for (int qg = 0; qg < 2; ++qg){ oaccT[i][qg][0]=0.f; oaccT[i][qg][1]=0.f; oaccT[i][qg][2]=0.f; oaccT[i][qg][3]=0.f; }
  float m0 = -3.0e38f, m1 = -3.0e38f, l0 = 0.f, l1 = 0.f;
  const float SCL = 0.125f * 1.44269504f;

  // staging constants
  const int krow = tid >> 3;
  const int kskc = (tid & 7) ^ (krow & 7);
  const int vp_  = tid >> 3;            // kv-pair 0..31 (kv = 2vp_, 2vp_+1)
  const int d0   = (tid & 7) * 8;       // this thread's 8 d-rows
  const int w16  = vp_ & 15;
  const int qpos = (w16 & 1) | (((w16 >> 3) & 1) << 1) | (((w16 >> 1) & 3) << 2);
  const int Pc   = ((vp_ >> 4) << 2) | (qpos >> 2);   // chunk (pre-swizzle)
  const int Ps   = qpos & 3;                          // pair slot in chunk

  #define KSTAGE(buf, t) { \
    const int kv0_ = (t) << 6; \
    gload_lds16(qkv + (size_t)(kv0_ + krow) * QKVC + koff + kskc * 8,      &sK[buf][(w * 64) * 8]); \
    gload_lds16(qkv + (size_t)(kv0_ + 32 + krow) * QKVC + koff + kskc * 8, &sK[buf][(256 + w * 64) * 8]); }

  #define VLOAD(t) { \
    const unsigned short* vp = qkv + (size_t)(((t) << 6) + vp_ * 2) * QKVC + voff + d0; \
    va = *(const bf16x8*)vp; \
    vb = *(const bf16x8*)(vp + QKVC); }

  #define VCOMMIT(buf) { \
    _Pragma("unroll") \
    for (int i = 0; i < 8; ++i){ \
      unsigned pk = (unsigned)(unsigned short)va[i] | ((unsigned)(unsigned short)vb[i] << 16); \
      *(unsigned*)&sVt[buf][(d0 + i) * 64 + ((Pc ^ (tid & 7) ^ i) << 3) + Ps * 2] = pk; \
    } }

  bf16x8 va, vb;
  KSTAGE(0, 0);
  VLOAD(0);
  VCOMMIT(0);

  for (int t64 = 0; t64 < 64; ++t64){
    const int cur = t64 & 1;
    __syncthreads();               // buf[cur] staged; buf[cur^1] free
    const bool pre = (t64 < 63);
    if (pre){
      KSTAGE(cur ^ 1, t64 + 1);
      VLOAD(t64 + 1);              // T14: loads land during QK+softmax+PV
    }

    // ---- QK^T (swapped): sf[nb][qg] = S^T[kv=16nb+4l4+r][q] ----
    f32x4 sf[4][2];
    #pragma unroll
    for (int i = 0; i < 4; ++i)
      #pragma unroll
      for (int qg = 0; qg < 2; ++qg){ sf[i][qg][0]=0.f; sf[i][qg][1]=0.f; sf[i][qg][2]=0.f; sf[i][qg][3]=0.f; }
    __builtin_amdgcn_s_setprio(1);
    #pragma unroll
    for (int ks = 0; ks < 2; ++ks){
      bf16x8 kf[4];
      #pragma unroll
      for (int nb = 0; nb < 4; ++nb){
        int row = 16 * nb + l15;
        kf[nb] = *(const bf16x8*)&sK[cur][(row * 8 + ((4 * ks + l4) ^ (row & 7))) * 8];
      }
      #pragma unroll
      for (int nb = 0; nb < 4; ++nb){
        sf[nb][0] = MFMA16(kf[nb], qf[0][ks], sf[nb][0]);
        sf[nb][1] = MFMA16(kf[nb], qf[1][ks], sf[nb][1]);
      }
    }
    __builtin_amdgcn_s_setprio(0);

    // ---- online softmax (per-lane rows, scaled-log2 domain) ----
    float mx0, mx1;
    {
      float a = sf[0][0][0], b = sf[0][1][0];
      #pragma unroll
      for (int nb = 0; nb < 4; ++nb)
        #pragma unroll
        for (int r = 0; r < 4; ++r){
          a = fmaxf(a, sf[nb][0][r]);
          b = fmaxf(b, sf[nb][1][r]);
        }
      a *= SCL; b *= SCL;
      a = fmaxf(a, __shfl_xor(a, 16)); a = fmaxf(a, __shfl_xor(a, 32));
      b = fmaxf(b, __shfl_xor(b, 16)); b = fmaxf(b, __shfl_xor(b, 32));
      mx0 = a; mx1 = b;
    }
    bool ok = (mx0 <= m0 + 8.f) && (mx1 <= m1 + 8.f);   // T13 defer-max
    if (!__all(ok)){
      float nm0 = fmaxf(m0, mx0), nm1 = fmaxf(m1, mx1);
      float c0 = __builtin_amdgcn_exp2f(m0 - nm0);
      float c1 = __builtin_amdgcn_exp2f(m1 - nm1);
      m0 = nm0; m1 = nm1; l0 *= c0; l1 *= c1;
      #pragma unroll
      for (int db = 0; db < 4; ++db)
        #pragma unroll
        for (int r = 0; r < 4; ++r){ oaccT[db][0][r] *= c0; oaccT[db][1][r] *= c1; }
    }
    unsigned pbw[2][2][4];   // [qg][ks][word]; slot j holds kv=32ks+16(j>>2)+4l4+(j&3)
    {
      float ps0 = 0.f, ps1 = 0.f;
      #pragma unroll
      for (int nb = 0; nb < 4; ++nb){
        float p0[4], p1[4];
        #pragma unroll
        for (int r = 0; r < 4; ++r){
          p0[r] = __builtin_amdgcn_exp2f(sf[nb][0][r] * SCL - m0); ps0 += p0[r];
          p1[r] = __builtin_amdgcn_exp2f(sf[nb][1][r] * SCL - m1); ps1 += p1[r];
        }
        pbw[0][nb >> 1][(nb & 1) * 2]     = cvtpk(p0[0], p0[1]);
        pbw[0][nb >> 1][(nb & 1) * 2 + 1] = cvtpk(p0[2], p0[3]);
        pbw[1][nb >> 1][(nb & 1) * 2]     = cvtpk(p1[0], p1[1]);
        pbw[1][nb >> 1][(nb & 1) * 2 + 1] = cvtpk(p1[2], p1[3]);
      }
      ps0 += __shfl_xor(ps0, 16); ps0 += __shfl_xor(ps0, 32);
      ps1 += __shfl_xor(ps1, 16); ps1 += __shfl_xor(ps1, 32);
      l0 += ps0; l1 += ps1;
    }

    // ---- O^T += V^T * P^T (in-register P, permuted-content V) ----
    __builtin_amdgcn_s_setprio(1);
    {
      bf16x8 vv[2][4];
      #pragma unroll
      for (int ks = 0; ks < 2; ++ks)
        #pragma unroll
        for (int db = 0; db < 4; ++db){
          int d = 16 * db + l15;
          int cp = (4 * ks + l4) ^ ((d >> 3) & 7) ^ (d & 7);
          vv[ks][db] = *(const bf16x8*)&sVt[cur][d * 64 + cp * 8];
        }
      union { unsigned uw[4]; bf16x8 v; } pb;
      #pragma unroll
      for (int qg = 0; qg < 2; ++qg){
        bf16x8 pb0, pb1;
        pb.uw[0]=pbw[qg][0][0]; pb.uw[1]=pbw[qg][0][1]; pb.uw[2]=pbw[qg][0][2]; pb.uw[3]=pbw[qg][0][3]; pb0 = pb.v;
        pb.uw[0]=pbw[qg][1][0]; pb.uw[1]=pbw[qg][1][1]; pb.uw[2]=pbw[qg][1][2]; pb.uw[3]=pbw[qg][1][3]; pb1 = pb.v;
        #pragma unroll
        for (int db = 0; db < 4; ++db){
          oaccT[db][qg] = MFMA16(vv[0][db], pb0, oaccT[db][qg]);
          oaccT[db][qg] = MFMA16(vv[1][db], pb1, oaccT[db][qg]);
        }
      }
    }
    __builtin_amdgcn_s_setprio(0);

    // ---- commit next tile's V (global loads have had the tile to land) ----
    if (pre) VCOMMIT(cur ^ 1);
  }

  // ---- epilogue: O^T -> O via per-wave scratch ----
  #pragma unroll
  for (int qg = 0; qg < 2; ++qg){
    float inv = 1.f / (qg ? l1 : l0);
    unsigned short* sPw = sEp[w];
    #pragma unroll
    for (int db = 0; db < 4; ++db)
      #pragma unroll
      for (int dw = 0; dw < 2; ++dw){
        unsigned pk = (unsigned)f2bf(oaccT[db][qg][2 * dw] * inv) |
                      ((unsigned)f2bf(oaccT[db][qg][2 * dw + 1] * inv) << 16);
        *(unsigned*)&sPw[l15 * 72 + 16 * db + 4 * l4 + 2 * dw] = pk;
      }
    int qe = lane >> 2, de = (lane & 3) * 16;
    bf16x8 r0 = *(const bf16x8*)&sPw[qe * 72 + de];
    bf16x8 r1 = *(const bf16x8*)&sPw[qe * 72 + de + 8];
    unsigned short* op = o + (size_t)(qbase + qg * 16 + qe) * EMB + head * HD + de;
    *(bf16x8*)op = r0;
    *(bf16x8*)(op + 8) = r1;
  }
  #undef KSTAGE
  #undef VLOAD
  #undef VCOMMIT
}

// ---------------- host launch ----------------
extern "C" void kernel_launch(void* const* d_in, const int* in_sizes, int n_in,
                              void* d_out, int out_size, void* d_ws, size_t ws_size,
                              hipStream_t stream)
{
  const float* x    = (const float*)d_in[0];
  const float* ln1w = (const float*)d_in[1];
  const float* ln1b = (const float*)d_in[2];
  const float* qkvw = (const float*)d_in[3];
  const float* qkvb = (const float*)d_in[4];
  const float* outw = (const float*)d_in[5];
  const float* outb = (const float*)d_in[6];
  const float* ln2w = (const float*)d_in[7];
  const float* ln2b = (const float*)d_in[8];
  const float* fc1w = (const float*)d_in[9];
  const float* fc1b = (const float*)d_in[10];
  const float* fc2w = (const float*)d_in[11];
  const float* fc2b = (const float*)d_in[12];
  float* out = (float*)d_out;

  char* ws = (char*)d_ws;
  unsigned short* wqkv = (unsigned short*)ws; ws += (size_t)QKVC * EMB * 2;
  unsigned short* wout = (unsigned short*)ws; ws += (size_t)EMB * EMB * 2;
  unsigned short* wfc1 = (unsigned short*)ws; ws += (size_t)HID * EMB * 2;
  unsigned short* wfc2 = (unsigned short*)ws; ws += (size_t)EMB * HID * 2;
  unsigned short* h1   = (unsigned short*)ws; ws += (size_t)SEQ * EMB * 2;   // reused as attn out
  unsigned short* qkv  = (unsigned short*)ws; ws += (size_t)SEQ * QKVC * 2;  // reused as h2
  unsigned short* h3   = (unsigned short*)ws; ws += (size_t)SEQ * HID * 2;
  unsigned short* attnb = h1;
  unsigned short* h2    = qkv;

  cvt_kernel<<<(QKVC * EMB / 4 + 255) / 256, 256, 0, stream>>>(qkvw, wqkv, QKVC * EMB);
  cvt_kernel<<<(EMB  * EMB / 4 + 255) / 256, 256, 0, stream>>>(outw, wout, EMB * EMB);
  cvt_kernel<<<(HID  * EMB / 4 + 255) / 256, 256, 0, stream>>>(fc1w, wfc1, HID * EMB);
  cvt_kernel<<<(EMB  * HID / 4 + 255) / 256, 256, 0, stream>>>(fc2w, wfc2, EMB * HID);

  ln_kernel<<<SEQ, 256, 0, stream>>>(x, ln1w, ln1b, h1);

  gemm_kernel<0, 128><<<dim3(QKVC / 128, SEQ / 128), 256, 0, stream>>>(
      h1, wqkv, qkvb, nullptr, qkv, nullptr, SEQ, QKVC, EMB);

  attn_kernel<<<SEQ / 128 * NH, 256, 0, stream>>>(qkv, attnb);

  gemm_kernel<2, 64><<<dim3(EMB / 64, SEQ / 128), 256, 0, stream>>>(
      attnb, wout, outb, x, nullptr, out, SEQ, EMB, EMB);

  ln_kernel<<<SEQ, 256, 0, stream>>>(out, ln2w, ln2b, h2);

  gemm_kernel<1, 128><<<dim3(HID / 128, SEQ / 128), 256, 0, stream>>>(
      h2, wfc1, fc1b, nullptr, h3, nullptr, SEQ, HID, EMB);

  gemm_kernel<2, 64><<<dim3(EMB / 64, SEQ / 128), 256, 0, stream>>>(
      h3, wfc2, fc2b, out, nullptr, out, SEQ, EMB, HID);
}